// Round 9
// baseline (484.273 us; speedup 1.0000x reference)
//
#include <hip/hip_runtime.h>
#include <hip/hip_bf16.h>
#include <cstdint>
#include <cstddef>

// Problem constants (B,S,D,H fixed by the reference)
#define Bc 4
#define Sc 2048
#define Dc 1024
#define Hc 16
// HD = 64

typedef __bf16 bf16;
typedef bf16  bf16x4 __attribute__((ext_vector_type(4)));
typedef bf16  bf16x8 __attribute__((ext_vector_type(8)));
typedef float f32x4  __attribute__((ext_vector_type(4)));

__device__ __forceinline__ void load_lds16(const bf16* g, bf16* l) {
    __builtin_amdgcn_global_load_lds((const __attribute__((address_space(1))) void*)g,
                                     (__attribute__((address_space(3))) void*)l,
                                     16, 0, 0);
}

// 16 fp32 -> two bf16x8
__device__ __forceinline__ void cvt16(const float* __restrict__ g,
                                      bf16x8& lo, bf16x8& hi) {
    const f32x4 a0 = *(const f32x4*)(g);
    const f32x4 a1 = *(const f32x4*)(g + 4);
    const f32x4 a2 = *(const f32x4*)(g + 8);
    const f32x4 a3 = *(const f32x4*)(g + 12);
#pragma unroll
    for (int j = 0; j < 4; j++) {
        lo[j]     = (bf16)a0[j];
        lo[j + 4] = (bf16)a1[j];
        hi[j]     = (bf16)a2[j];
        hi[j + 4] = (bf16)a3[j];
    }
}

__device__ __forceinline__ void store_relu(float* p, float v) { *p = fmaxf(v, 0.0f); }
__device__ __forceinline__ void store_relu(bf16*  p, float v) { *p = (bf16)fmaxf(v, 0.0f); }

// ---------------------------------------------------------------------------
// fp32 -> bf16 conversion (16 elems/thread)
// ---------------------------------------------------------------------------
__global__ __launch_bounds__(256)
void cvt_f32_bf16(const float* __restrict__ src, bf16* __restrict__ dst, int n16) {
    const int idx = blockIdx.x * 256 + threadIdx.x;
    if (idx >= n16) return;
    bf16x8 lo, hi;
    cvt16(src + (size_t)idx * 16, lo, hi);
    *(bf16x8*)(dst + (size_t)idx * 16)     = lo;
    *(bf16x8*)(dst + (size_t)idx * 16 + 8) = hi;
}

// 4 weight matrices in one launch (dst blocks contiguous: Wqb|Wkb|Wvb|Wob).
__global__ __launch_bounds__(256)
void cvt_w4(const float* __restrict__ s0, const float* __restrict__ s1,
            const float* __restrict__ s2, const float* __restrict__ s3,
            bf16* __restrict__ dst) {
    const float* srcs[4] = {s0, s1, s2, s3};
    const float* src = srcs[blockIdx.y];
    const int idx = blockIdx.x * 256 + threadIdx.x;
    bf16x8 lo, hi;
    cvt16(src + (size_t)idx * 16, lo, hi);
    bf16* d = dst + (size_t)blockIdx.y * ((size_t)Dc * Dc) + (size_t)idx * 16;
    *(bf16x8*)d       = lo;
    *(bf16x8*)(d + 8) = hi;
}

// ---------------------------------------------------------------------------
// GEMM: C = relu(A[M,K] @ W[N,K]^T + bias), bf16 in, fp32 accum.
// ROUND-5 CONFIG (best measured, unchanged). 128x64 tile, BK=64, single-
// buffered global_load_lds staging, grid 64x16 = 1024 blocks (4/CU).
// LDS XOR swizzle: logical (row,col) stored at row*64 + (col ^ ((row&7)*8)).
// TR=true: V-projection epilogue writes per-head transposed Vt_g[b][h][hd][s].
// ---------------------------------------------------------------------------
#define BM 128
#define BN 64
#define BK 64

template <typename TC, bool TR>
__global__ __launch_bounds__(256)
void gemm_bb(const bf16* __restrict__ A, const bf16* __restrict__ W,
             const float* __restrict__ bias, TC* __restrict__ C,
             int M, int N, int K) {
    __shared__ __align__(16) char pool[24576];
    bf16* lA = (bf16*)pool;                        // [BM*BK] = 16 KB
    bf16* lB = (bf16*)(pool + 16384);              // [BN*BK] =  8 KB

    const int t    = threadIdx.x;
    const int lane = t & 63;
    const int wave = t >> 6;
    const int l15  = lane & 15;
    const int quad = lane >> 4;

    const int m0 = blockIdx.x * BM;
    const int n0 = blockIdx.y * BN;
    const int wm = (wave >> 1) * 64;   // 0 / 64
    const int wn = (wave & 1) * 32;    // 0 / 32

    f32x4 acc[4][2] = {};

    const int srow = t >> 3;                          // 0..31
    const int cg   = (((t & 7) ^ (srow & 7)) << 3);   // swizzled logical col
    const bf16* gA = A + (size_t)(m0 + srow) * K + cg;
    const bf16* gW = W + (size_t)(n0 + srow) * K + cg;
    bf16* lA0 = lA + t * 8;
    bf16* lB0 = lB + t * 8;

    for (int k0 = 0; k0 < K; k0 += BK) {
        __syncthreads();               // previous tiles fully consumed
#pragma unroll
        for (int c = 0; c < 4; c++)
            load_lds16(gA + (size_t)(32 * c) * K, lA0 + c * 2048);
#pragma unroll
        for (int c = 0; c < 2; c++)
            load_lds16(gW + (size_t)(32 * c) * K, lB0 + c * 2048);
        gA += BK; gW += BK;
        __syncthreads();               // drains vmcnt -> tiles published

#pragma unroll
        for (int ks = 0; ks < 2; ks++) {
            bf16x8 af[4], bfr[2];
            const int colp = ((((ks << 2) | quad) ^ (l15 & 7)) << 3);
#pragma unroll
            for (int mt = 0; mt < 4; mt++) {
                const int row = wm + mt * 16 + l15;
                af[mt] = *(const bf16x8*)(lA + row * BK + colp);
            }
#pragma unroll
            for (int nt = 0; nt < 2; nt++) {
                const int row = wn + nt * 16 + l15;
                bfr[nt] = *(const bf16x8*)(lB + row * BK + colp);
            }
#pragma unroll
            for (int mt = 0; mt < 4; mt++)
#pragma unroll
                for (int nt = 0; nt < 2; nt++)
                    acc[mt][nt] = __builtin_amdgcn_mfma_f32_16x16x32_bf16(
                        af[mt], bfr[nt], acc[mt][nt], 0, 0, 0);
        }
    }

    if constexpr (!TR) {
#pragma unroll
        for (int nt = 0; nt < 2; nt++) {
            const int col = n0 + wn + nt * 16 + l15;
            const float bv = bias[col];
#pragma unroll
            for (int mt = 0; mt < 4; mt++) {
                const int rowb = m0 + wm + mt * 16 + quad * 4;
#pragma unroll
                for (int i = 0; i < 4; i++)
                    store_relu(&C[(size_t)(rowb + i) * N + col], acc[mt][nt][i] + bv);
            }
        }
    } else {
        __syncthreads();               // everyone done reading lA/lB
        bf16* trp = (bf16*)pool;       // tr[w][r][c] = trp[(w*32+r)*72 + c]
#pragma unroll
        for (int nt = 0; nt < 2; nt++) {
            const int col = n0 + wn + nt * 16 + l15;
            const float bv = bias[col];
#pragma unroll
            for (int mt = 0; mt < 4; mt++)
#pragma unroll
                for (int i = 0; i < 4; i++)
                    trp[((wave * 32) + nt * 16 + l15) * 72 + mt * 16 + quad * 4 + i] =
                        (bf16)fmaxf(acc[mt][nt][i] + bv, 0.0f);
        }
        __syncthreads();
        const int r2 = lane >> 3;          // 0..7
        const int c8 = (lane & 7) * 8;     // 0..56
#pragma unroll
        for (int rr = 0; rr < 4; rr++) {
            const int rt = rr * 8 + r2;                  // 0..31 (hd-dim col)
            const bf16x8 vv = *(const bf16x8*)&trp[((wave * 32) + rt) * 72 + c8];
            const int cg2 = n0 + wn + rt;                // global col
            const int h   = cg2 >> 6, hd = cg2 & 63;
            const int mg  = m0 + wm + c8;                // global row base
            const int b   = mg >> 11, s = mg & (Sc - 1);
            bf16* dst = (bf16*)C + ((size_t)(b * Hc + h) * 64 + hd) * Sc + s;
            *(bf16x8*)dst = vv;
        }
    }
}

// ---------------------------------------------------------------------------
// Flash attention — BARRIER-FREE, L2-DIRECT (this round).
// K/V working set is L2-resident by construction: bh on blockIdx.x makes
// XCD = bh%8, so each XCD hosts 8 bh x 8 q-blocks whose K+V slices total
// 8 x 512 KB = 4 MB = one XCD L2. So: read K/V fragments DIRECTLY from
// global into registers (m169 precedent: drop LDS staging of L2-fit data).
// No Kl/Vl, no ds_writes, ZERO __syncthreads — waves fully independent.
// Fragment regs double-buffered: tile kt+1's 16 b128 loads issue before
// tile kt's compute (one compute phase ~1500cyc covers L2 ~200cyc).
// Pl (per-wave P^T round-trip) stays, with R8's XOR swizzle; same-wave DS
// ordering is HW-guaranteed, no barriers needed. LDS 49152 -> 32768 B.
// __launch_bounds__(256,2) pins VGPR <= 256 (2 waves/SIMD = the grid cap).
// Fixed-max softmax: p = exp2(s) (post-ReLU scores bounded), ones-MFMA
// denominator, raw v_exp_f32, s_setprio around MFMA clusters.
// V pre-transposed per head: Vt_g[b][h][hd][s]. O accumulated transposed.
// ---------------------------------------------------------------------------
#define QI 4

__global__ __launch_bounds__(256, 2)
void attn_flash(const bf16* __restrict__ Qh, const bf16* __restrict__ Kh,
                const bf16* __restrict__ Vt_g, bf16* __restrict__ Y) {
    __shared__ __align__(16) bf16 Pl[4][64][64];    // per-wave P^T, swizzled

    const int t    = threadIdx.x;
    const int lane = t & 63;
    const int wave = t >> 6;
    const int l15  = lane & 15;
    const int quad = lane >> 4;
    const int rswz = (l15 & 7) * 8;     // swizzle key (row = ...+l15)

    const int bh = blockIdx.x;          // 0..63  (x so same-bh blocks share XCD)
    const int qt = blockIdx.y;          // 0..7
    const int b  = bh >> 4;
    const int h  = bh & 15;
    const int q0 = qt * 256;
    const size_t rowbase = (size_t)b * Sc;
    const size_t vhead   = (size_t)(b * Hc + h) * 64;

    const float qscale = 0.125f * 1.44269504f;
    bf16x8 qf[QI][2];
#pragma unroll
    for (int qi = 0; qi < QI; qi++) {
        const bf16* qp = Qh + (rowbase + q0 + wave * 64 + qi * 16 + l15) * (size_t)Dc + h * 64;
#pragma unroll
        for (int ks = 0; ks < 2; ks++) {
            const bf16x8 raw = *(const bf16x8*)(qp + ks * 32 + quad * 8);
#pragma unroll
            for (int j = 0; j < 8; j++) qf[qi][ks][j] = (bf16)((float)raw[j] * qscale);
        }
    }

    bf16x8 ones;
#pragma unroll
    for (int j = 0; j < 8; j++) ones[j] = (bf16)1.0f;

    f32x4 yacc[QI][4] = {};             // O^T: col=query=l15, row=hd
    f32x4 sacc[QI]    = {};             // denominator: all rows = sum_k p

    // per-lane fragment base pointers (16B per lane, 64B/row across quads)
    const bf16* kbase = Kh   + (rowbase + l15) * (size_t)Dc + h * 64 + quad * 8;
    const bf16* vbase = Vt_g + (vhead   + l15) * (size_t)Sc + quad * 8;

    auto load_tile = [&](bf16x8 (&kd)[4][2], bf16x8 (&vd)[4][2], int kb) {
#pragma unroll
        for (int mt = 0; mt < 4; mt++) {
#pragma unroll
            for (int ks = 0; ks < 2; ks++) {
                kd[mt][ks] = *(const bf16x8*)(kbase + (size_t)(kb + mt * 16) * Dc + ks * 32);
                vd[mt][ks] = *(const bf16x8*)(vbase + (size_t)(mt * 16) * Sc + kb + ks * 32);
            }
        }
    };

    auto compute_tile = [&](const bf16x8 (&kc)[4][2], const bf16x8 (&vc)[4][2]) {
        // ---- phase A: per qi QK^T -> exp2 -> P store ----
#pragma unroll
        for (int qi = 0; qi < QI; qi++) {
            f32x4 s[4];
            __builtin_amdgcn_s_setprio(1);
#pragma unroll
            for (int mt = 0; mt < 4; mt++) {
                s[mt] = (f32x4){0.f, 0.f, 0.f, 0.f};
                s[mt] = __builtin_amdgcn_mfma_f32_16x16x32_bf16(
                    kc[mt][0], qf[qi][0], s[mt], 0, 0, 0);
                s[mt] = __builtin_amdgcn_mfma_f32_16x16x32_bf16(
                    kc[mt][1], qf[qi][1], s[mt], 0, 0, 0);
            }
            __builtin_amdgcn_s_setprio(0);
#pragma unroll
            for (int mt = 0; mt < 4; mt++) {
                bf16x4 pk;
#pragma unroll
                for (int i = 0; i < 4; i++)
                    pk[i] = (bf16)__builtin_amdgcn_exp2f(s[mt][i]);
                *(bf16x4*)&Pl[wave][qi * 16 + l15][(mt * 16 + quad * 4) ^ rswz] = pk;
            }
        }

        // ---- phase B: all pf reads, then denominator + PV MFMAs ----
        bf16x8 pf[QI][2];
#pragma unroll
        for (int qi = 0; qi < QI; qi++) {
            pf[qi][0] = *(const bf16x8*)&Pl[wave][qi * 16 + l15][(quad * 8) ^ rswz];
            pf[qi][1] = *(const bf16x8*)&Pl[wave][qi * 16 + l15][(32 + quad * 8) ^ rswz];
        }
        __builtin_amdgcn_s_setprio(1);
#pragma unroll
        for (int qi = 0; qi < QI; qi++) {
            sacc[qi] = __builtin_amdgcn_mfma_f32_16x16x32_bf16(ones, pf[qi][0], sacc[qi], 0, 0, 0);
            sacc[qi] = __builtin_amdgcn_mfma_f32_16x16x32_bf16(ones, pf[qi][1], sacc[qi], 0, 0, 0);
#pragma unroll
            for (int nt = 0; nt < 4; nt++) {
                yacc[qi][nt] = __builtin_amdgcn_mfma_f32_16x16x32_bf16(
                    vc[nt][0], pf[qi][0], yacc[qi][nt], 0, 0, 0);
                yacc[qi][nt] = __builtin_amdgcn_mfma_f32_16x16x32_bf16(
                    vc[nt][1], pf[qi][1], yacc[qi][nt], 0, 0, 0);
            }
        }
        __builtin_amdgcn_s_setprio(0);
    };

    constexpr int NT = Sc / 64;         // 32 key tiles
    bf16x8 kA[4][2], vA[4][2], kB[4][2], vB[4][2];
    load_tile(kA, vA, 0);
#pragma unroll 1
    for (int kt = 0; kt < NT; kt += 2) {
        load_tile(kB, vB, (kt + 1) * 64);      // prefetch odd tile
        compute_tile(kA, vA);
        if (kt + 2 < NT)
            load_tile(kA, vA, (kt + 2) * 64);  // prefetch next even tile
        compute_tile(kB, vB);
    }

    // ---- normalize (denominator replicated in every lane), store ----
#pragma unroll
    for (int qi = 0; qi < QI; qi++) {
        const float inv = 1.0f / sacc[qi][0];
        bf16* yp = Y + (rowbase + q0 + wave * 64 + qi * 16 + l15) * (size_t)Dc + h * 64;
#pragma unroll
        for (int nt = 0; nt < 4; nt++)
#pragma unroll
            for (int i = 0; i < 4; i++)
                yp[nt * 16 + quad * 4 + i] = (bf16)(yacc[qi][nt][i] * inv);
    }
}

// ---------------------------------------------------------------------------
extern "C" void kernel_launch(void* const* d_in, const int* in_sizes, int n_in,
                              void* d_out, int out_size, void* d_ws, size_t ws_size,
                              hipStream_t stream) {
    const float* q  = (const float*)d_in[0];
    const float* k  = (const float*)d_in[1];
    const float* v  = (const float*)d_in[2];
    const float* Wq = (const float*)d_in[3];
    const float* bq = (const float*)d_in[4];
    const float* Wk = (const float*)d_in[5];
    const float* bk = (const float*)d_in[6];
    const float* Wv = (const float*)d_in[7];
    const float* bv = (const float*)d_in[8];
    const float* Wo = (const float*)d_in[9];
    const float* bo = (const float*)d_in[10];
    float* out = (float*)d_out;

    const int M = Bc * Sc;   // 8192
    const int N = Dc;        // 1024
    const int K = Dc;        // 1024
    const size_t E  = (size_t)Bc * Sc * Dc;  // 8388608
    const size_t EW = (size_t)Dc * Dc;       // 1048576

    // d_out: Qh | Kh (bf16; dead before final GEMM writes fp32).
    // d_ws:  tmpA | VtG | Wqb|Wkb|Wvb|Wob  (41.9 MB; proven capacity).
    bf16* Qh   = (bf16*)d_out;
    bf16* Kh   = Qh + E;
    bf16* tmpA = (bf16*)d_ws;
    bf16* VtG  = tmpA + E;
    bf16* Wqb  = VtG + E;
    bf16* Wkb  = Wqb + EW;
    bf16* Wvb  = Wkb + EW;
    bf16* Wob  = Wvb + EW;

    const int n16  = (int)(E / 16);          // 524288
    const int n16w = (int)(EW / 16);         // 65536
    dim3 gc(n16 / 256);                      // 2048
    dim3 gw4(n16w / 256, 4);                 // 256 x 4 (all four weights)
    dim3 gg(M / BM, N / BN);                 // 64 x 16 = 1024 blocks (4/CU)
    dim3 ga(Bc * Hc, Sc / 256);              // 64 x 8 (bh on x: XCD locality)

    cvt_w4<<<gw4, 256, 0, stream>>>(Wq, Wk, Wv, Wo, Wqb);

    cvt_f32_bf16<<<gc, 256, 0, stream>>>(q, tmpA, n16);
    gemm_bb<bf16, false><<<gg, 256, 0, stream>>>(tmpA, Wqb, bq, Qh, M, N, K);

    cvt_f32_bf16<<<gc, 256, 0, stream>>>(k, tmpA, n16);
    gemm_bb<bf16, false><<<gg, 256, 0, stream>>>(tmpA, Wkb, bk, Kh, M, N, K);

    cvt_f32_bf16<<<gc, 256, 0, stream>>>(v, tmpA, n16);
    gemm_bb<bf16, true><<<gg, 256, 0, stream>>>(tmpA, Wvb, bv, VtG, M, N, K);

    attn_flash<<<ga, 256, 0, stream>>>(Qh, Kh, VtG, tmpA);

    gemm_bb<float, false><<<gg, 256, 0, stream>>>(tmpA, Wob, bo, out, M, N, K);
}

// Round 10
// 364.609 us; speedup vs baseline: 1.3282x; 1.3282x over previous
//
#include <hip/hip_runtime.h>
#include <hip/hip_bf16.h>
#include <cstdint>
#include <cstddef>

// Problem constants (B,S,D,H fixed by the reference)
#define Bc 4
#define Sc 2048
#define Dc 1024
#define Hc 16
// HD = 64

typedef __bf16 bf16;
typedef bf16  bf16x4 __attribute__((ext_vector_type(4)));
typedef bf16  bf16x8 __attribute__((ext_vector_type(8)));
typedef float f32x4  __attribute__((ext_vector_type(4)));

__device__ __forceinline__ void load_lds16(const bf16* g, bf16* l) {
    __builtin_amdgcn_global_load_lds((const __attribute__((address_space(1))) void*)g,
                                     (__attribute__((address_space(3))) void*)l,
                                     16, 0, 0);
}

// 16 fp32 -> two bf16x8
__device__ __forceinline__ void cvt16(const float* __restrict__ g,
                                      bf16x8& lo, bf16x8& hi) {
    const f32x4 a0 = *(const f32x4*)(g);
    const f32x4 a1 = *(const f32x4*)(g + 4);
    const f32x4 a2 = *(const f32x4*)(g + 8);
    const f32x4 a3 = *(const f32x4*)(g + 12);
#pragma unroll
    for (int j = 0; j < 4; j++) {
        lo[j]     = (bf16)a0[j];
        lo[j + 4] = (bf16)a1[j];
        hi[j]     = (bf16)a2[j];
        hi[j + 4] = (bf16)a3[j];
    }
}

__device__ __forceinline__ void store_relu(float* p, float v) { *p = fmaxf(v, 0.0f); }
__device__ __forceinline__ void store_relu(bf16*  p, float v) { *p = (bf16)fmaxf(v, 0.0f); }

// ---------------------------------------------------------------------------
// fp32 -> bf16 conversion (16 elems/thread) — serial-fallback path
// ---------------------------------------------------------------------------
__global__ __launch_bounds__(256)
void cvt_f32_bf16(const float* __restrict__ src, bf16* __restrict__ dst, int n16) {
    const int idx = blockIdx.x * 256 + threadIdx.x;
    if (idx >= n16) return;
    bf16x8 lo, hi;
    cvt16(src + (size_t)idx * 16, lo, hi);
    *(bf16x8*)(dst + (size_t)idx * 16)     = lo;
    *(bf16x8*)(dst + (size_t)idx * 16 + 8) = hi;
}

// 4 weight matrices in one launch (dst blocks contiguous: Wqb|Wkb|Wvb|Wob).
__global__ __launch_bounds__(256)
void cvt_w4(const float* __restrict__ s0, const float* __restrict__ s1,
            const float* __restrict__ s2, const float* __restrict__ s3,
            bf16* __restrict__ dst) {
    const float* srcs[4] = {s0, s1, s2, s3};
    const float* src = srcs[blockIdx.y];
    const int idx = blockIdx.x * 256 + threadIdx.x;
    bf16x8 lo, hi;
    cvt16(src + (size_t)idx * 16, lo, hi);
    bf16* d = dst + (size_t)blockIdx.y * ((size_t)Dc * Dc) + (size_t)idx * 16;
    *(bf16x8*)d       = lo;
    *(bf16x8*)(d + 8) = hi;
}

// q,k,v in one launch (dst blocks contiguous: Aq|Ak|Av) — batched path
__global__ __launch_bounds__(256)
void cvt_in3(const float* __restrict__ s0, const float* __restrict__ s1,
             const float* __restrict__ s2, bf16* __restrict__ dst) {
    const float* srcs[3] = {s0, s1, s2};
    const float* src = srcs[blockIdx.y];
    const int idx = blockIdx.x * 256 + threadIdx.x;
    bf16x8 lo, hi;
    cvt16(src + (size_t)idx * 16, lo, hi);
    bf16* d = dst + (size_t)blockIdx.y * ((size_t)Bc * Sc * Dc) + (size_t)idx * 16;
    *(bf16x8*)d       = lo;
    *(bf16x8*)(d + 8) = hi;
}

// ---------------------------------------------------------------------------
// GEMM core (R5/R8 proven config): C = relu(A[M,K] @ W[N,K]^T + bias).
// 128x64 tile, BK=64 (16 k-iters), single-buffered global_load_lds staging,
// 2 barriers/iter, grid 64x16 (4 blocks/CU). LDS XOR swizzle:
// logical (row,col) stored at row*64 + (col ^ ((row&7)*8)) -> ~0 conflicts.
// ---------------------------------------------------------------------------
#define BM 128
#define BN 64
#define BK 64

template <typename TC, bool TR>
__device__ __forceinline__
void gemm_body(const bf16* __restrict__ A, const bf16* __restrict__ W,
               const float* __restrict__ bias, TC* __restrict__ C,
               char* pool, int M, int N, int K) {
    bf16* lA = (bf16*)pool;                        // [BM*BK] = 16 KB
    bf16* lB = (bf16*)(pool + 16384);              // [BN*BK] =  8 KB

    const int t    = threadIdx.x;
    const int lane = t & 63;
    const int wave = t >> 6;
    const int l15  = lane & 15;
    const int quad = lane >> 4;

    const int m0 = blockIdx.x * BM;
    const int n0 = blockIdx.y * BN;
    const int wm = (wave >> 1) * 64;   // 0 / 64
    const int wn = (wave & 1) * 32;    // 0 / 32

    f32x4 acc[4][2] = {};

    const int srow = t >> 3;                          // 0..31
    const int cg   = (((t & 7) ^ (srow & 7)) << 3);   // swizzled logical col
    const bf16* gA = A + (size_t)(m0 + srow) * K + cg;
    const bf16* gW = W + (size_t)(n0 + srow) * K + cg;
    bf16* lA0 = lA + t * 8;
    bf16* lB0 = lB + t * 8;

    for (int k0 = 0; k0 < K; k0 += BK) {
        __syncthreads();               // previous tiles fully consumed
#pragma unroll
        for (int c = 0; c < 4; c++)
            load_lds16(gA + (size_t)(32 * c) * K, lA0 + c * 2048);
#pragma unroll
        for (int c = 0; c < 2; c++)
            load_lds16(gW + (size_t)(32 * c) * K, lB0 + c * 2048);
        gA += BK; gW += BK;
        __syncthreads();               // drains vmcnt -> tiles published

#pragma unroll
        for (int ks = 0; ks < 2; ks++) {
            bf16x8 af[4], bfr[2];
            const int colp = ((((ks << 2) | quad) ^ (l15 & 7)) << 3);
#pragma unroll
            for (int mt = 0; mt < 4; mt++) {
                const int row = wm + mt * 16 + l15;
                af[mt] = *(const bf16x8*)(lA + row * BK + colp);
            }
#pragma unroll
            for (int nt = 0; nt < 2; nt++) {
                const int row = wn + nt * 16 + l15;
                bfr[nt] = *(const bf16x8*)(lB + row * BK + colp);
            }
#pragma unroll
            for (int mt = 0; mt < 4; mt++)
#pragma unroll
                for (int nt = 0; nt < 2; nt++)
                    acc[mt][nt] = __builtin_amdgcn_mfma_f32_16x16x32_bf16(
                        af[mt], bfr[nt], acc[mt][nt], 0, 0, 0);
        }
    }

    if constexpr (!TR) {
        // C/D layout: col = lane&15, row = quad*4 + i
#pragma unroll
        for (int nt = 0; nt < 2; nt++) {
            const int col = n0 + wn + nt * 16 + l15;
            const float bv = bias[col];
#pragma unroll
            for (int mt = 0; mt < 4; mt++) {
                const int rowb = m0 + wm + mt * 16 + quad * 4;
#pragma unroll
                for (int i = 0; i < 4; i++)
                    store_relu(&C[(size_t)(rowb + i) * N + col], acc[mt][nt][i] + bv);
            }
        }
    } else {
        // Transposed per-head epilogue into Vt_g[b][h][hd][s].
        __syncthreads();               // everyone done reading lA/lB
        bf16* trp = (bf16*)pool;       // tr[w][r][c] = trp[(w*32+r)*72 + c]
#pragma unroll
        for (int nt = 0; nt < 2; nt++) {
            const int col = n0 + wn + nt * 16 + l15;
            const float bv = bias[col];
#pragma unroll
            for (int mt = 0; mt < 4; mt++)
#pragma unroll
                for (int i = 0; i < 4; i++)
                    trp[((wave * 32) + nt * 16 + l15) * 72 + mt * 16 + quad * 4 + i] =
                        (bf16)fmaxf(acc[mt][nt][i] + bv, 0.0f);
        }
        __syncthreads();
        const int r2 = lane >> 3;          // 0..7
        const int c8 = (lane & 7) * 8;     // 0..56
#pragma unroll
        for (int rr = 0; rr < 4; rr++) {
            const int rt = rr * 8 + r2;                  // 0..31 (hd-dim col)
            const bf16x8 vv = *(const bf16x8*)&trp[((wave * 32) + rt) * 72 + c8];
            const int cg2 = n0 + wn + rt;                // global col
            const int h   = cg2 >> 6, hd = cg2 & 63;
            const int mg  = m0 + wm + c8;                // global row base
            const int b   = mg >> 11, s = mg & (Sc - 1);
            bf16* dst = (bf16*)C + ((size_t)(b * Hc + h) * 64 + hd) * Sc + s;
            *(bf16x8*)dst = vv;
        }
    }
}

template <typename TC, bool TR>
__global__ __launch_bounds__(256)
void gemm_bb(const bf16* __restrict__ A, const bf16* __restrict__ W,
             const float* __restrict__ bias, TC* __restrict__ C,
             int M, int N, int K) {
    __shared__ __align__(16) char pool[24576];
    gemm_body<TC, TR>(A, W, bias, C, pool, M, N, K);
}

// Batched QKV projection: blockIdx.z in {0,1,2} selects (A, W, bias, C);
// z<2 writes Qh/Kh (normal epilogue), z==2 writes VtG (TR epilogue).
// Body identical to gemm_bb — R7 measured z-batching perf-neutral
// (134 us = 3 x 44.7); saves 2 launch gaps + enables single cvt_in3.
__global__ __launch_bounds__(256)
void gemm_qkv3(const bf16* __restrict__ Aall, const bf16* __restrict__ Wall,
               const float* __restrict__ bq, const float* __restrict__ bk,
               const float* __restrict__ bv, bf16* __restrict__ Qh,
               bf16* __restrict__ vtg, int M, int N, int K) {
    __shared__ __align__(16) char pool[24576];
    const int z = blockIdx.z;
    const size_t E = (size_t)Bc * Sc * Dc;
    const bf16*  A    = Aall + (size_t)z * E;
    const bf16*  W    = Wall + (size_t)z * ((size_t)Dc * Dc);
    const float* bias = (z == 0) ? bq : (z == 1) ? bk : bv;
    if (z < 2)
        gemm_body<bf16, false>(A, W, bias, Qh + (size_t)z * E, pool, M, N, K);
    else
        gemm_body<bf16, true>(A, W, bias, vtg, pool, M, N, K);
}

// ---------------------------------------------------------------------------
// Flash attention — R8 version (best measured: 121.3 us), UNCHANGED.
// Transposed-score fixed-max softmax (post-ReLU scores bounded): p=exp2(s),
// no running max/rescale; denominator via ones-MFMA, applied at end.
// Single-buffered K/V (2 barriers/tile), batched phase A (all qi
// QK+exp2+P-store) then phase B (all pf reads + denominator/PV), T14
// issue-early global loads, raw v_exp_f32, s_setprio, bh-on-x grid (XCD
// locality: FETCH 41 MB). K/V/P LDS in stride-64 + XOR-chunk swizzle
// (col ^ ((row&7)*8)): conflicts 10.5M -> 4.2M measured.
// V pre-transposed per head: Vt_g[b][h][hd][s]. O accumulated transposed.
// ---------------------------------------------------------------------------
#define QI 4

__global__ __launch_bounds__(256)
void attn_flash(const bf16* __restrict__ Qh, const bf16* __restrict__ Kh,
                const bf16* __restrict__ Vt_g, bf16* __restrict__ Y) {
    __shared__ __align__(16) bf16 Kl[64][64];       // [key][hd]  swz   8192 B
    __shared__ __align__(16) bf16 Vl[64][64];       // [hd][key]  swz   8192 B
    __shared__ __align__(16) bf16 Pl[4][64][64];    // per-wave P^T swz 32768 B

    const int t    = threadIdx.x;
    const int lane = t & 63;
    const int wave = t >> 6;
    const int l15  = lane & 15;
    const int quad = lane >> 4;
    const int rswz = (l15 & 7) * 8;     // read-side swizzle key (row = ...+l15)

    const int bh = blockIdx.x;          // 0..63  (x so same-bh blocks share XCD)
    const int qt = blockIdx.y;          // 0..7
    const int b  = bh >> 4;
    const int h  = bh & 15;
    const int q0 = qt * 256;
    const size_t rowbase = (size_t)b * Sc;
    const size_t vhead   = (size_t)(b * Hc + h) * 64;

    const float qscale = 0.125f * 1.44269504f;
    bf16x8 qf[QI][2];
#pragma unroll
    for (int qi = 0; qi < QI; qi++) {
        const bf16* qp = Qh + (rowbase + q0 + wave * 64 + qi * 16 + l15) * (size_t)Dc + h * 64;
#pragma unroll
        for (int ks = 0; ks < 2; ks++) {
            const bf16x8 raw = *(const bf16x8*)(qp + ks * 32 + quad * 8);
#pragma unroll
            for (int j = 0; j < 8; j++) qf[qi][ks][j] = (bf16)((float)raw[j] * qscale);
        }
    }

    bf16x8 ones;
#pragma unroll
    for (int j = 0; j < 8; j++) ones[j] = (bf16)1.0f;

    f32x4 yacc[QI][4] = {};             // O^T: col=query=l15, row=hd
    f32x4 sacc[QI]    = {};             // denominator: all rows = sum_k p

    // staging map: thread covers row sr, logical cols [sc, sc+16)
    const int sr = t >> 2;
    const int sc = (t & 3) * 16;
    const int wswz = (sr & 7) * 8;      // write-side swizzle key
    const int sc0 = sc ^ wswz;          // swizzled chunk addresses (8-aligned)
    const int sc1 = (sc + 8) ^ wswz;
    constexpr int NT = Sc / 64;         // 32 key tiles

    const bf16* kp = Kh + (rowbase + sr) * (size_t)Dc + h * 64 + sc;
    const bf16* vp = Vt_g + (vhead + sr) * (size_t)Sc + sc;
    bf16x8 k0 = *(const bf16x8*)kp;
    bf16x8 k1 = *(const bf16x8*)(kp + 8);
    bf16x8 v0 = *(const bf16x8*)vp;
    bf16x8 v1 = *(const bf16x8*)(vp + 8);

    for (int kt = 0; kt < NT; kt++) {
        __syncthreads();                // prev tile fully consumed by all waves
        *(bf16x8*)&Kl[sr][sc0] = k0;
        *(bf16x8*)&Kl[sr][sc1] = k1;
        *(bf16x8*)&Vl[sr][sc0] = v0;
        *(bf16x8*)&Vl[sr][sc1] = v1;
        __syncthreads();                // tile published

        // T14 issue-early: fetch NEXT tile into regs; latency hides under
        // this tile's compute.
        if (kt + 1 < NT) {
            kp += (size_t)64 * Dc;
            vp += 64;
            k0 = *(const bf16x8*)kp;
            k1 = *(const bf16x8*)(kp + 8);
            v0 = *(const bf16x8*)vp;
            v1 = *(const bf16x8*)(vp + 8);
        }

        // ---- K fragments (A-operand [m=key][k=hd]), shared across all qi ----
        bf16x8 kf[4][2];
#pragma unroll
        for (int mt = 0; mt < 4; mt++) {
            kf[mt][0] = *(const bf16x8*)&Kl[mt * 16 + l15][(quad * 8) ^ rswz];
            kf[mt][1] = *(const bf16x8*)&Kl[mt * 16 + l15][(32 + quad * 8) ^ rswz];
        }

        // ---- phase A: per qi QK^T -> exp2 -> P store (round-trips batched) ----
#pragma unroll
        for (int qi = 0; qi < QI; qi++) {
            f32x4 s[4];
            __builtin_amdgcn_s_setprio(1);
#pragma unroll
            for (int mt = 0; mt < 4; mt++) {
                s[mt] = (f32x4){0.f, 0.f, 0.f, 0.f};
                s[mt] = __builtin_amdgcn_mfma_f32_16x16x32_bf16(
                    kf[mt][0], qf[qi][0], s[mt], 0, 0, 0);
                s[mt] = __builtin_amdgcn_mfma_f32_16x16x32_bf16(
                    kf[mt][1], qf[qi][1], s[mt], 0, 0, 0);
            }
            __builtin_amdgcn_s_setprio(0);
#pragma unroll
            for (int mt = 0; mt < 4; mt++) {
                bf16x4 pk;
#pragma unroll
                for (int i = 0; i < 4; i++)
                    pk[i] = (bf16)__builtin_amdgcn_exp2f(s[mt][i]);
                *(bf16x4*)&Pl[wave][qi * 16 + l15][(mt * 16 + quad * 4) ^ rswz] = pk;
            }
        }

        // ---- V fragments (A-operand [m=hd][k=key]) ----
        bf16x8 vf[4][2];
#pragma unroll
        for (int nt = 0; nt < 4; nt++) {
            vf[nt][0] = *(const bf16x8*)&Vl[nt * 16 + l15][(quad * 8) ^ rswz];
            vf[nt][1] = *(const bf16x8*)&Vl[nt * 16 + l15][(32 + quad * 8) ^ rswz];
        }

        // ---- phase B: all pf reads, then all denominator + PV MFMAs ----
        bf16x8 pf[QI][2];
#pragma unroll
        for (int qi = 0; qi < QI; qi++) {
            pf[qi][0] = *(const bf16x8*)&Pl[wave][qi * 16 + l15][(quad * 8) ^ rswz];
            pf[qi][1] = *(const bf16x8*)&Pl[wave][qi * 16 + l15][(32 + quad * 8) ^ rswz];
        }
        __builtin_amdgcn_s_setprio(1);
#pragma unroll
        for (int qi = 0; qi < QI; qi++) {
            sacc[qi] = __builtin_amdgcn_mfma_f32_16x16x32_bf16(ones, pf[qi][0], sacc[qi], 0, 0, 0);
            sacc[qi] = __builtin_amdgcn_mfma_f32_16x16x32_bf16(ones, pf[qi][1], sacc[qi], 0, 0, 0);
#pragma unroll
            for (int nt = 0; nt < 4; nt++) {
                yacc[qi][nt] = __builtin_amdgcn_mfma_f32_16x16x32_bf16(
                    vf[nt][0], pf[qi][0], yacc[qi][nt], 0, 0, 0);
                yacc[qi][nt] = __builtin_amdgcn_mfma_f32_16x16x32_bf16(
                    vf[nt][1], pf[qi][1], yacc[qi][nt], 0, 0, 0);
            }
        }
        __builtin_amdgcn_s_setprio(0);
    }

    // ---- normalize (denominator replicated in every lane), store ----
#pragma unroll
    for (int qi = 0; qi < QI; qi++) {
        const float inv = 1.0f / sacc[qi][0];
        bf16* yp = Y + (rowbase + q0 + wave * 64 + qi * 16 + l15) * (size_t)Dc + h * 64;
#pragma unroll
        for (int nt = 0; nt < 4; nt++)
#pragma unroll
            for (int i = 0; i < 4; i++)
                yp[nt * 16 + quad * 4 + i] = (bf16)(yacc[qi][nt][i] * inv);
    }
}

// ---------------------------------------------------------------------------
extern "C" void kernel_launch(void* const* d_in, const int* in_sizes, int n_in,
                              void* d_out, int out_size, void* d_ws, size_t ws_size,
                              hipStream_t stream) {
    const float* q  = (const float*)d_in[0];
    const float* k  = (const float*)d_in[1];
    const float* v  = (const float*)d_in[2];
    const float* Wq = (const float*)d_in[3];
    const float* bq = (const float*)d_in[4];
    const float* Wk = (const float*)d_in[5];
    const float* bk = (const float*)d_in[6];
    const float* Wv = (const float*)d_in[7];
    const float* bv = (const float*)d_in[8];
    const float* Wo = (const float*)d_in[9];
    const float* bo = (const float*)d_in[10];
    float* out = (float*)d_out;

    const int M = Bc * Sc;   // 8192
    const int N = Dc;        // 1024
    const int K = Dc;        // 1024
    const size_t E  = (size_t)Bc * Sc * Dc;  // 8388608
    const size_t EW = (size_t)Dc * Dc;       // 1048576

    // d_out: Qh | Kh (bf16; dead before final GEMM writes fp32).
    bf16* Qh = (bf16*)d_out;

    const int n16  = (int)(E / 16);          // 524288
    const int n16w = (int)(EW / 16);         // 65536
    dim3 gw4(n16w / 256, 4);                 // 256 x 4 (all four weights)
    dim3 gg(M / BM, N / BN);                 // 64 x 16 = 1024 blocks (4/CU)
    dim3 ga(Bc * Hc, Sc / 256);              // 64 x 8 (bh on x: XCD locality)

    // Batched layout needs Aq|Ak|Av|VtG|W4 = (4E + 4EW) bf16 = 75.5 MB.
    const size_t need_batched = (4 * E + 4 * EW) * sizeof(bf16);

    if (ws_size >= need_batched) {
        // ---- 5-launch path: cut ~4 inter-launch gaps ----
        bf16* Aq  = (bf16*)d_ws;             // also attn-output buffer later
        bf16* VtG = Aq + 3 * E;
        bf16* Wqb = VtG + E;
        bf16* Wob = Wqb + 3 * EW;
        bf16* tmpA = Aq;                     // attn Y (Aq dead after GEMMs)

        dim3 gc3(n16 / 256, 3);              // 2048 x 3
        dim3 gg3(M / BM, N / BN, 3);         // 64 x 16 x 3

        cvt_w4<<<gw4, 256, 0, stream>>>(Wq, Wk, Wv, Wo, Wqb);
        cvt_in3<<<gc3, 256, 0, stream>>>(q, k, v, Aq);
        gemm_qkv3<<<gg3, 256, 0, stream>>>(Aq, Wqb, bq, bk, bv, Qh, VtG, M, N, K);
        attn_flash<<<ga, 256, 0, stream>>>(Qh, Qh + E, VtG, tmpA);
        gemm_bb<float, false><<<gg, 256, 0, stream>>>(tmpA, Wob, bo, out, M, N, K);
    } else {
        // ---- R8 serial fallback (proven): tmpA | VtG | W4 = 41.9 MB ----
        bf16* tmpA = (bf16*)d_ws;
        bf16* VtG  = tmpA + E;
        bf16* Wqb  = VtG + E;
        bf16* Wkb  = Wqb + EW;
        bf16* Wvb  = Wkb + EW;
        bf16* Wob  = Wvb + EW;
        bf16* Kh   = Qh + E;

        dim3 gc(n16 / 256);                  // 2048

        cvt_w4<<<gw4, 256, 0, stream>>>(Wq, Wk, Wv, Wo, Wqb);

        cvt_f32_bf16<<<gc, 256, 0, stream>>>(q, tmpA, n16);
        gemm_bb<bf16, false><<<gg, 256, 0, stream>>>(tmpA, Wqb, bq, Qh, M, N, K);

        cvt_f32_bf16<<<gc, 256, 0, stream>>>(k, tmpA, n16);
        gemm_bb<bf16, false><<<gg, 256, 0, stream>>>(tmpA, Wkb, bk, Kh, M, N, K);

        cvt_f32_bf16<<<gc, 256, 0, stream>>>(v, tmpA, n16);
        gemm_bb<bf16, true><<<gg, 256, 0, stream>>>(tmpA, Wvb, bv, VtG, M, N, K);

        attn_flash<<<ga, 256, 0, stream>>>(Qh, Kh, VtG, tmpA);

        gemm_bb<float, false><<<gg, 256, 0, stream>>>(tmpA, Wob, bo, out, M, N, K);
    }
}

// Round 11
// 362.850 us; speedup vs baseline: 1.3346x; 1.0048x over previous
//
#include <hip/hip_runtime.h>
#include <hip/hip_bf16.h>
#include <cstdint>
#include <cstddef>

// Problem constants (B,S,D,H fixed by the reference)
#define Bc 4
#define Sc 2048
#define Dc 1024
#define Hc 16
// HD = 64

typedef __bf16 bf16;
typedef bf16  bf16x4 __attribute__((ext_vector_type(4)));
typedef bf16  bf16x8 __attribute__((ext_vector_type(8)));
typedef float f32x4  __attribute__((ext_vector_type(4)));

__device__ __forceinline__ void load_lds16(const bf16* g, bf16* l) {
    __builtin_amdgcn_global_load_lds((const __attribute__((address_space(1))) void*)g,
                                     (__attribute__((address_space(3))) void*)l,
                                     16, 0, 0);
}

// 16 fp32 -> two bf16x8
__device__ __forceinline__ void cvt16(const float* __restrict__ g,
                                      bf16x8& lo, bf16x8& hi) {
    const f32x4 a0 = *(const f32x4*)(g);
    const f32x4 a1 = *(const f32x4*)(g + 4);
    const f32x4 a2 = *(const f32x4*)(g + 8);
    const f32x4 a3 = *(const f32x4*)(g + 12);
#pragma unroll
    for (int j = 0; j < 4; j++) {
        lo[j]     = (bf16)a0[j];
        lo[j + 4] = (bf16)a1[j];
        hi[j]     = (bf16)a2[j];
        hi[j + 4] = (bf16)a3[j];
    }
}

__device__ __forceinline__ void store_relu(float* p, float v) { *p = fmaxf(v, 0.0f); }
__device__ __forceinline__ void store_relu(bf16*  p, float v) { *p = (bf16)fmaxf(v, 0.0f); }

// ---------------------------------------------------------------------------
// fp32 -> bf16 conversion (16 elems/thread) — serial-fallback path
// ---------------------------------------------------------------------------
__global__ __launch_bounds__(256)
void cvt_f32_bf16(const float* __restrict__ src, bf16* __restrict__ dst, int n16) {
    const int idx = blockIdx.x * 256 + threadIdx.x;
    if (idx >= n16) return;
    bf16x8 lo, hi;
    cvt16(src + (size_t)idx * 16, lo, hi);
    *(bf16x8*)(dst + (size_t)idx * 16)     = lo;
    *(bf16x8*)(dst + (size_t)idx * 16 + 8) = hi;
}

// 4 weight matrices in one launch (dst blocks contiguous: Wqb|Wkb|Wvb|Wob).
__global__ __launch_bounds__(256)
void cvt_w4(const float* __restrict__ s0, const float* __restrict__ s1,
            const float* __restrict__ s2, const float* __restrict__ s3,
            bf16* __restrict__ dst) {
    const float* srcs[4] = {s0, s1, s2, s3};
    const float* src = srcs[blockIdx.y];
    const int idx = blockIdx.x * 256 + threadIdx.x;
    bf16x8 lo, hi;
    cvt16(src + (size_t)idx * 16, lo, hi);
    bf16* d = dst + (size_t)blockIdx.y * ((size_t)Dc * Dc) + (size_t)idx * 16;
    *(bf16x8*)d       = lo;
    *(bf16x8*)(d + 8) = hi;
}

// q,k,v in one launch (dst blocks contiguous: Aq|Ak|Av) — batched path
__global__ __launch_bounds__(256)
void cvt_in3(const float* __restrict__ s0, const float* __restrict__ s1,
             const float* __restrict__ s2, bf16* __restrict__ dst) {
    const float* srcs[3] = {s0, s1, s2};
    const float* src = srcs[blockIdx.y];
    const int idx = blockIdx.x * 256 + threadIdx.x;
    bf16x8 lo, hi;
    cvt16(src + (size_t)idx * 16, lo, hi);
    bf16* d = dst + (size_t)blockIdx.y * ((size_t)Bc * Sc * Dc) + (size_t)idx * 16;
    *(bf16x8*)d       = lo;
    *(bf16x8*)(d + 8) = hi;
}

// ---------------------------------------------------------------------------
// GEMM core (R5/R8 proven config): C = relu(A[M,K] @ W[N,K]^T + bias).
// 128x64 tile, BK=64 (16 k-iters), single-buffered global_load_lds staging,
// 2 barriers/iter, grid 64x16 (4 blocks/CU). LDS XOR swizzle:
// logical (row,col) stored at row*64 + (col ^ ((row&7)*8)) -> ~0 conflicts.
// ---------------------------------------------------------------------------
#define BM 128
#define BN 64
#define BK 64

template <typename TC, bool TR>
__device__ __forceinline__
void gemm_body(const bf16* __restrict__ A, const bf16* __restrict__ W,
               const float* __restrict__ bias, TC* __restrict__ C,
               char* pool, int M, int N, int K) {
    bf16* lA = (bf16*)pool;                        // [BM*BK] = 16 KB
    bf16* lB = (bf16*)(pool + 16384);              // [BN*BK] =  8 KB

    const int t    = threadIdx.x;
    const int lane = t & 63;
    const int wave = t >> 6;
    const int l15  = lane & 15;
    const int quad = lane >> 4;

    const int m0 = blockIdx.x * BM;
    const int n0 = blockIdx.y * BN;
    const int wm = (wave >> 1) * 64;   // 0 / 64
    const int wn = (wave & 1) * 32;    // 0 / 32

    f32x4 acc[4][2] = {};

    const int srow = t >> 3;                          // 0..31
    const int cg   = (((t & 7) ^ (srow & 7)) << 3);   // swizzled logical col
    const bf16* gA = A + (size_t)(m0 + srow) * K + cg;
    const bf16* gW = W + (size_t)(n0 + srow) * K + cg;
    bf16* lA0 = lA + t * 8;
    bf16* lB0 = lB + t * 8;

    for (int k0 = 0; k0 < K; k0 += BK) {
        __syncthreads();               // previous tiles fully consumed
#pragma unroll
        for (int c = 0; c < 4; c++)
            load_lds16(gA + (size_t)(32 * c) * K, lA0 + c * 2048);
#pragma unroll
        for (int c = 0; c < 2; c++)
            load_lds16(gW + (size_t)(32 * c) * K, lB0 + c * 2048);
        gA += BK; gW += BK;
        __syncthreads();               // drains vmcnt -> tiles published

#pragma unroll
        for (int ks = 0; ks < 2; ks++) {
            bf16x8 af[4], bfr[2];
            const int colp = ((((ks << 2) | quad) ^ (l15 & 7)) << 3);
#pragma unroll
            for (int mt = 0; mt < 4; mt++) {
                const int row = wm + mt * 16 + l15;
                af[mt] = *(const bf16x8*)(lA + row * BK + colp);
            }
#pragma unroll
            for (int nt = 0; nt < 2; nt++) {
                const int row = wn + nt * 16 + l15;
                bfr[nt] = *(const bf16x8*)(lB + row * BK + colp);
            }
#pragma unroll
            for (int mt = 0; mt < 4; mt++)
#pragma unroll
                for (int nt = 0; nt < 2; nt++)
                    acc[mt][nt] = __builtin_amdgcn_mfma_f32_16x16x32_bf16(
                        af[mt], bfr[nt], acc[mt][nt], 0, 0, 0);
        }
    }

    if constexpr (!TR) {
        // C/D layout: col = lane&15, row = quad*4 + i
#pragma unroll
        for (int nt = 0; nt < 2; nt++) {
            const int col = n0 + wn + nt * 16 + l15;
            const float bv = bias[col];
#pragma unroll
            for (int mt = 0; mt < 4; mt++) {
                const int rowb = m0 + wm + mt * 16 + quad * 4;
#pragma unroll
                for (int i = 0; i < 4; i++)
                    store_relu(&C[(size_t)(rowb + i) * N + col], acc[mt][nt][i] + bv);
            }
        }
    } else {
        // Transposed per-head epilogue into Vt_g[b][h][hd][s].
        __syncthreads();               // everyone done reading lA/lB
        bf16* trp = (bf16*)pool;       // tr[w][r][c] = trp[(w*32+r)*72 + c]
#pragma unroll
        for (int nt = 0; nt < 2; nt++) {
            const int col = n0 + wn + nt * 16 + l15;
            const float bv = bias[col];
#pragma unroll
            for (int mt = 0; mt < 4; mt++)
#pragma unroll
                for (int i = 0; i < 4; i++)
                    trp[((wave * 32) + nt * 16 + l15) * 72 + mt * 16 + quad * 4 + i] =
                        (bf16)fmaxf(acc[mt][nt][i] + bv, 0.0f);
        }
        __syncthreads();
        const int r2 = lane >> 3;          // 0..7
        const int c8 = (lane & 7) * 8;     // 0..56
#pragma unroll
        for (int rr = 0; rr < 4; rr++) {
            const int rt = rr * 8 + r2;                  // 0..31 (hd-dim col)
            const bf16x8 vv = *(const bf16x8*)&trp[((wave * 32) + rt) * 72 + c8];
            const int cg2 = n0 + wn + rt;                // global col
            const int h   = cg2 >> 6, hd = cg2 & 63;
            const int mg  = m0 + wm + c8;                // global row base
            const int b   = mg >> 11, s = mg & (Sc - 1);
            bf16* dst = (bf16*)C + ((size_t)(b * Hc + h) * 64 + hd) * Sc + s;
            *(bf16x8*)dst = vv;
        }
    }
}

template <typename TC, bool TR>
__global__ __launch_bounds__(256)
void gemm_bb(const bf16* __restrict__ A, const bf16* __restrict__ W,
             const float* __restrict__ bias, TC* __restrict__ C,
             int M, int N, int K) {
    __shared__ __align__(16) char pool[24576];
    gemm_body<TC, TR>(A, W, bias, C, pool, M, N, K);
}

// Batched QKV projection: blockIdx.z in {0,1,2} selects (A, W, bias, C);
// z<2 writes Qh/Kh (normal epilogue), z==2 writes VtG (TR epilogue).
__global__ __launch_bounds__(256)
void gemm_qkv3(const bf16* __restrict__ Aall, const bf16* __restrict__ Wall,
               const float* __restrict__ bq, const float* __restrict__ bk,
               const float* __restrict__ bv, bf16* __restrict__ Qh,
               bf16* __restrict__ vtg, int M, int N, int K) {
    __shared__ __align__(16) char pool[24576];
    const int z = blockIdx.z;
    const size_t E = (size_t)Bc * Sc * Dc;
    const bf16*  A    = Aall + (size_t)z * E;
    const bf16*  W    = Wall + (size_t)z * ((size_t)Dc * Dc);
    const float* bias = (z == 0) ? bq : (z == 1) ? bk : bv;
    if (z < 2)
        gemm_body<bf16, false>(A, W, bias, Qh + (size_t)z * E, pool, M, N, K);
    else
        gemm_body<bf16, true>(A, W, bias, vtg, pool, M, N, K);
}

// ---------------------------------------------------------------------------
// Flash attention — R8 inner structure, NARROWED to 128 queries/block (QI=2).
// Rationale (R10 counters): no pipe above ~26% (MFMA 25, VALU 35 incl MFMA,
// LDS ~13%, trans ~11%) -> issue/latency-starved at 2 waves/SIMD (grid 512
// blocks = 2 blocks/CU). QI=2 shrinks Pl to [4][32][64] -> LDS 32 KB and
// grid 64x16 = 1024 blocks = 4 blocks/CU = 4 waves/SIMD (VGPR ~100).
// Cost: per-CU K/V staging + kf/vf reads double (LDS 13->26%, FETCH 41->80MB
// expected) — both far from limits. R1's 128q attempt never had this benefit
// (55 KB LDS capped it at 2 blocks/CU).
// Fixed-max softmax p=exp2(s) (post-ReLU scores bounded), ones-MFMA
// denominator, raw v_exp_f32, s_setprio, T14 issue-early K/V loads,
// stride-64 XOR-chunk swizzle (conflicts 10.5M -> 4.2M measured),
// bh-on-x grid (XCD locality, preserved: XCD = linear%8 = bh%8).
// V pre-transposed per head: Vt_g[b][h][hd][s]. O accumulated transposed.
// ---------------------------------------------------------------------------
#define QI 2

__global__ __launch_bounds__(256)
void attn_flash(const bf16* __restrict__ Qh, const bf16* __restrict__ Kh,
                const bf16* __restrict__ Vt_g, bf16* __restrict__ Y) {
    __shared__ __align__(16) bf16 Kl[64][64];       // [key][hd]  swz   8192 B
    __shared__ __align__(16) bf16 Vl[64][64];       // [hd][key]  swz   8192 B
    __shared__ __align__(16) bf16 Pl[4][32][64];    // per-wave P^T swz 16384 B

    const int t    = threadIdx.x;
    const int lane = t & 63;
    const int wave = t >> 6;
    const int l15  = lane & 15;
    const int quad = lane >> 4;
    const int rswz = (l15 & 7) * 8;     // read-side swizzle key (row = ...+l15)

    const int bh = blockIdx.x;          // 0..63  (x so same-bh blocks share XCD)
    const int qt = blockIdx.y;          // 0..15
    const int b  = bh >> 4;
    const int h  = bh & 15;
    const int q0 = qt * 128;
    const size_t rowbase = (size_t)b * Sc;
    const size_t vhead   = (size_t)(b * Hc + h) * 64;

    const float qscale = 0.125f * 1.44269504f;
    bf16x8 qf[QI][2];
#pragma unroll
    for (int qi = 0; qi < QI; qi++) {
        const bf16* qp = Qh + (rowbase + q0 + wave * 32 + qi * 16 + l15) * (size_t)Dc + h * 64;
#pragma unroll
        for (int ks = 0; ks < 2; ks++) {
            const bf16x8 raw = *(const bf16x8*)(qp + ks * 32 + quad * 8);
#pragma unroll
            for (int j = 0; j < 8; j++) qf[qi][ks][j] = (bf16)((float)raw[j] * qscale);
        }
    }

    bf16x8 ones;
#pragma unroll
    for (int j = 0; j < 8; j++) ones[j] = (bf16)1.0f;

    f32x4 yacc[QI][4] = {};             // O^T: col=query=l15, row=hd
    f32x4 sacc[QI]    = {};             // denominator: all rows = sum_k p

    // staging map: thread covers row sr, logical cols [sc, sc+16)
    const int sr = t >> 2;
    const int sc = (t & 3) * 16;
    const int wswz = (sr & 7) * 8;      // write-side swizzle key
    const int sc0 = sc ^ wswz;          // swizzled chunk addresses (8-aligned)
    const int sc1 = (sc + 8) ^ wswz;
    constexpr int NT = Sc / 64;         // 32 key tiles

    const bf16* kp = Kh + (rowbase + sr) * (size_t)Dc + h * 64 + sc;
    const bf16* vp = Vt_g + (vhead + sr) * (size_t)Sc + sc;
    bf16x8 k0 = *(const bf16x8*)kp;
    bf16x8 k1 = *(const bf16x8*)(kp + 8);
    bf16x8 v0 = *(const bf16x8*)vp;
    bf16x8 v1 = *(const bf16x8*)(vp + 8);

    for (int kt = 0; kt < NT; kt++) {
        __syncthreads();                // prev tile fully consumed by all waves
        *(bf16x8*)&Kl[sr][sc0] = k0;
        *(bf16x8*)&Kl[sr][sc1] = k1;
        *(bf16x8*)&Vl[sr][sc0] = v0;
        *(bf16x8*)&Vl[sr][sc1] = v1;
        __syncthreads();                // tile published

        // T14 issue-early: fetch NEXT tile into regs; latency hides under
        // this tile's compute.
        if (kt + 1 < NT) {
            kp += (size_t)64 * Dc;
            vp += 64;
            k0 = *(const bf16x8*)kp;
            k1 = *(const bf16x8*)(kp + 8);
            v0 = *(const bf16x8*)vp;
            v1 = *(const bf16x8*)(vp + 8);
        }

        // ---- K fragments (A-operand [m=key][k=hd]), shared across all qi ----
        bf16x8 kf[4][2];
#pragma unroll
        for (int mt = 0; mt < 4; mt++) {
            kf[mt][0] = *(const bf16x8*)&Kl[mt * 16 + l15][(quad * 8) ^ rswz];
            kf[mt][1] = *(const bf16x8*)&Kl[mt * 16 + l15][(32 + quad * 8) ^ rswz];
        }

        // ---- phase A: per qi QK^T -> exp2 -> P store (round-trips batched) ----
#pragma unroll
        for (int qi = 0; qi < QI; qi++) {
            f32x4 s[4];
            __builtin_amdgcn_s_setprio(1);
#pragma unroll
            for (int mt = 0; mt < 4; mt++) {
                s[mt] = (f32x4){0.f, 0.f, 0.f, 0.f};
                s[mt] = __builtin_amdgcn_mfma_f32_16x16x32_bf16(
                    kf[mt][0], qf[qi][0], s[mt], 0, 0, 0);
                s[mt] = __builtin_amdgcn_mfma_f32_16x16x32_bf16(
                    kf[mt][1], qf[qi][1], s[mt], 0, 0, 0);
            }
            __builtin_amdgcn_s_setprio(0);
#pragma unroll
            for (int mt = 0; mt < 4; mt++) {
                bf16x4 pk;
#pragma unroll
                for (int i = 0; i < 4; i++)
                    pk[i] = (bf16)__builtin_amdgcn_exp2f(s[mt][i]);
                *(bf16x4*)&Pl[wave][qi * 16 + l15][(mt * 16 + quad * 4) ^ rswz] = pk;
            }
        }

        // ---- V fragments (A-operand [m=hd][k=key]) ----
        bf16x8 vf[4][2];
#pragma unroll
        for (int nt = 0; nt < 4; nt++) {
            vf[nt][0] = *(const bf16x8*)&Vl[nt * 16 + l15][(quad * 8) ^ rswz];
            vf[nt][1] = *(const bf16x8*)&Vl[nt * 16 + l15][(32 + quad * 8) ^ rswz];
        }

        // ---- phase B: all pf reads, then all denominator + PV MFMAs ----
        bf16x8 pf[QI][2];
#pragma unroll
        for (int qi = 0; qi < QI; qi++) {
            pf[qi][0] = *(const bf16x8*)&Pl[wave][qi * 16 + l15][(quad * 8) ^ rswz];
            pf[qi][1] = *(const bf16x8*)&Pl[wave][qi * 16 + l15][(32 + quad * 8) ^ rswz];
        }
        __builtin_amdgcn_s_setprio(1);
#pragma unroll
        for (int qi = 0; qi < QI; qi++) {
            sacc[qi] = __builtin_amdgcn_mfma_f32_16x16x32_bf16(ones, pf[qi][0], sacc[qi], 0, 0, 0);
            sacc[qi] = __builtin_amdgcn_mfma_f32_16x16x32_bf16(ones, pf[qi][1], sacc[qi], 0, 0, 0);
#pragma unroll
            for (int nt = 0; nt < 4; nt++) {
                yacc[qi][nt] = __builtin_amdgcn_mfma_f32_16x16x32_bf16(
                    vf[nt][0], pf[qi][0], yacc[qi][nt], 0, 0, 0);
                yacc[qi][nt] = __builtin_amdgcn_mfma_f32_16x16x32_bf16(
                    vf[nt][1], pf[qi][1], yacc[qi][nt], 0, 0, 0);
            }
        }
        __builtin_amdgcn_s_setprio(0);
    }

    // ---- normalize (denominator replicated in every lane), store ----
#pragma unroll
    for (int qi = 0; qi < QI; qi++) {
        const float inv = 1.0f / sacc[qi][0];
        bf16* yp = Y + (rowbase + q0 + wave * 32 + qi * 16 + l15) * (size_t)Dc + h * 64;
#pragma unroll
        for (int nt = 0; nt < 4; nt++)
#pragma unroll
            for (int i = 0; i < 4; i++)
                yp[nt * 16 + quad * 4 + i] = (bf16)(yacc[qi][nt][i] * inv);
    }
}

// ---------------------------------------------------------------------------
extern "C" void kernel_launch(void* const* d_in, const int* in_sizes, int n_in,
                              void* d_out, int out_size, void* d_ws, size_t ws_size,
                              hipStream_t stream) {
    const float* q  = (const float*)d_in[0];
    const float* k  = (const float*)d_in[1];
    const float* v  = (const float*)d_in[2];
    const float* Wq = (const float*)d_in[3];
    const float* bq = (const float*)d_in[4];
    const float* Wk = (const float*)d_in[5];
    const float* bk = (const float*)d_in[6];
    const float* Wv = (const float*)d_in[7];
    const float* bv = (const float*)d_in[8];
    const float* Wo = (const float*)d_in[9];
    const float* bo = (const float*)d_in[10];
    float* out = (float*)d_out;

    const int M = Bc * Sc;   // 8192
    const int N = Dc;        // 1024
    const int K = Dc;        // 1024
    const size_t E  = (size_t)Bc * Sc * Dc;  // 8388608
    const size_t EW = (size_t)Dc * Dc;       // 1048576

    // d_out: Qh | Kh (bf16; dead before final GEMM writes fp32).
    bf16* Qh = (bf16*)d_out;

    const int n16  = (int)(E / 16);          // 524288
    const int n16w = (int)(EW / 16);         // 65536
    dim3 gw4(n16w / 256, 4);                 // 256 x 4 (all four weights)
    dim3 gg(M / BM, N / BN);                 // 64 x 16 = 1024 blocks (4/CU)
    dim3 ga(Bc * Hc, Sc / 128);              // 64 x 16 (bh on x: XCD locality)

    // Batched layout needs Aq|Ak|Av|VtG|W4 = (4E + 4EW) bf16 = 75.5 MB.
    const size_t need_batched = (4 * E + 4 * EW) * sizeof(bf16);

    if (ws_size >= need_batched) {
        // ---- 5-launch path (R10 best): cut inter-launch gaps ----
        bf16* Aq  = (bf16*)d_ws;             // also attn-output buffer later
        bf16* VtG = Aq + 3 * E;
        bf16* Wqb = VtG + E;
        bf16* Wob = Wqb + 3 * EW;
        bf16* tmpA = Aq;                     // attn Y (Aq dead after GEMMs)

        dim3 gc3(n16 / 256, 3);              // 2048 x 3
        dim3 gg3(M / BM, N / BN, 3);         // 64 x 16 x 3

        cvt_w4<<<gw4, 256, 0, stream>>>(Wq, Wk, Wv, Wo, Wqb);
        cvt_in3<<<gc3, 256, 0, stream>>>(q, k, v, Aq);
        gemm_qkv3<<<gg3, 256, 0, stream>>>(Aq, Wqb, bq, bk, bv, Qh, VtG, M, N, K);
        attn_flash<<<ga, 256, 0, stream>>>(Qh, Qh + E, VtG, tmpA);
        gemm_bb<float, false><<<gg, 256, 0, stream>>>(tmpA, Wob, bo, out, M, N, K);
    } else {
        // ---- R8 serial fallback (proven): tmpA | VtG | W4 = 41.9 MB ----
        bf16* tmpA = (bf16*)d_ws;
        bf16* VtG  = tmpA + E;
        bf16* Wqb  = VtG + E;
        bf16* Wkb  = Wqb + EW;
        bf16* Wvb  = Wkb + EW;
        bf16* Wob  = Wvb + EW;
        bf16* Kh   = Qh + E;

        dim3 gc(n16 / 256);                  // 2048

        cvt_w4<<<gw4, 256, 0, stream>>>(Wq, Wk, Wv, Wo, Wqb);

        cvt_f32_bf16<<<gc, 256, 0, stream>>>(q, tmpA, n16);
        gemm_bb<bf16, false><<<gg, 256, 0, stream>>>(tmpA, Wqb, bq, Qh, M, N, K);

        cvt_f32_bf16<<<gc, 256, 0, stream>>>(k, tmpA, n16);
        gemm_bb<bf16, false><<<gg, 256, 0, stream>>>(tmpA, Wkb, bk, Kh, M, N, K);

        cvt_f32_bf16<<<gc, 256, 0, stream>>>(v, tmpA, n16);
        gemm_bb<bf16, true><<<gg, 256, 0, stream>>>(tmpA, Wvb, bv, VtG, M, N, K);

        attn_flash<<<ga, 256, 0, stream>>>(Qh, Kh, VtG, tmpA);

        gemm_bb<float, false><<<gg, 256, 0, stream>>>(tmpA, Wob, bo, out, M, N, K);
    }
}

// Round 13
// 362.131 us; speedup vs baseline: 1.3373x; 1.0020x over previous
//
#include <hip/hip_runtime.h>
#include <hip/hip_bf16.h>
#include <cstdint>
#include <cstddef>

// Problem constants (B,S,D,H fixed by the reference)
#define Bc 4
#define Sc 2048
#define Dc 1024
#define Hc 16
// HD = 64

typedef __bf16 bf16;
typedef bf16  bf16x4 __attribute__((ext_vector_type(4)));
typedef bf16  bf16x8 __attribute__((ext_vector_type(8)));
typedef float f32x4  __attribute__((ext_vector_type(4)));

__device__ __forceinline__ void load_lds16(const bf16* g, bf16* l) {
    __builtin_amdgcn_global_load_lds((const __attribute__((address_space(1))) void*)g,
                                     (__attribute__((address_space(3))) void*)l,
                                     16, 0, 0);
}

// 16 fp32 -> two bf16x8
__device__ __forceinline__ void cvt16(const float* __restrict__ g,
                                      bf16x8& lo, bf16x8& hi) {
    const f32x4 a0 = *(const f32x4*)(g);
    const f32x4 a1 = *(const f32x4*)(g + 4);
    const f32x4 a2 = *(const f32x4*)(g + 8);
    const f32x4 a3 = *(const f32x4*)(g + 12);
#pragma unroll
    for (int j = 0; j < 4; j++) {
        lo[j]     = (bf16)a0[j];
        lo[j + 4] = (bf16)a1[j];
        hi[j]     = (bf16)a2[j];
        hi[j + 4] = (bf16)a3[j];
    }
}

__device__ __forceinline__ void store_relu(float* p, float v) { *p = fmaxf(v, 0.0f); }
__device__ __forceinline__ void store_relu(bf16*  p, float v) { *p = (bf16)fmaxf(v, 0.0f); }

// ---------------------------------------------------------------------------
// fp32 -> bf16 conversion (16 elems/thread) — serial-fallback path
// ---------------------------------------------------------------------------
__global__ __launch_bounds__(256)
void cvt_f32_bf16(const float* __restrict__ src, bf16* __restrict__ dst, int n16) {
    const int idx = blockIdx.x * 256 + threadIdx.x;
    if (idx >= n16) return;
    bf16x8 lo, hi;
    cvt16(src + (size_t)idx * 16, lo, hi);
    *(bf16x8*)(dst + (size_t)idx * 16)     = lo;
    *(bf16x8*)(dst + (size_t)idx * 16 + 8) = hi;
}

// 4 weight matrices in one launch (dst blocks contiguous: Wqb|Wkb|Wvb|Wob).
__global__ __launch_bounds__(256)
void cvt_w4(const float* __restrict__ s0, const float* __restrict__ s1,
            const float* __restrict__ s2, const float* __restrict__ s3,
            bf16* __restrict__ dst) {
    const float* srcs[4] = {s0, s1, s2, s3};
    const float* src = srcs[blockIdx.y];
    const int idx = blockIdx.x * 256 + threadIdx.x;
    bf16x8 lo, hi;
    cvt16(src + (size_t)idx * 16, lo, hi);
    bf16* d = dst + (size_t)blockIdx.y * ((size_t)Dc * Dc) + (size_t)idx * 16;
    *(bf16x8*)d       = lo;
    *(bf16x8*)(d + 8) = hi;
}

// q,k,v in one launch (dst blocks contiguous: Aq|Ak|Av) — batched path
__global__ __launch_bounds__(256)
void cvt_in3(const float* __restrict__ s0, const float* __restrict__ s1,
             const float* __restrict__ s2, bf16* __restrict__ dst) {
    const float* srcs[3] = {s0, s1, s2};
    const float* src = srcs[blockIdx.y];
    const int idx = blockIdx.x * 256 + threadIdx.x;
    bf16x8 lo, hi;
    cvt16(src + (size_t)idx * 16, lo, hi);
    bf16* d = dst + (size_t)blockIdx.y * ((size_t)Bc * Sc * Dc) + (size_t)idx * 16;
    *(bf16x8*)d       = lo;
    *(bf16x8*)(d + 8) = hi;
}

// ---------------------------------------------------------------------------
// GEMM core (R5/R8 proven config): C = relu(A[M,K] @ W[N,K]^T + bias).
// 128x64 tile, BK=64 (16 k-iters), single-buffered global_load_lds staging,
// 2 barriers/iter, grid 64x16 (4 blocks/CU). LDS XOR swizzle:
// logical (row,col) stored at row*64 + (col ^ ((row&7)*8)) -> ~0 conflicts.
// ---------------------------------------------------------------------------
#define BM 128
#define BN 64
#define BK 64

template <typename TC, bool TR>
__device__ __forceinline__
void gemm_body(const bf16* __restrict__ A, const bf16* __restrict__ W,
               const float* __restrict__ bias, TC* __restrict__ C,
               char* pool, int M, int N, int K) {
    bf16* lA = (bf16*)pool;                        // [BM*BK] = 16 KB
    bf16* lB = (bf16*)(pool + 16384);              // [BN*BK] =  8 KB

    const int t    = threadIdx.x;
    const int lane = t & 63;
    const int wave = t >> 6;
    const int l15  = lane & 15;
    const int quad = lane >> 4;

    const int m0 = blockIdx.x * BM;
    const int n0 = blockIdx.y * BN;
    const int wm = (wave >> 1) * 64;   // 0 / 64
    const int wn = (wave & 1) * 32;    // 0 / 32

    f32x4 acc[4][2] = {};

    const int srow = t >> 3;                          // 0..31
    const int cg   = (((t & 7) ^ (srow & 7)) << 3);   // swizzled logical col
    const bf16* gA = A + (size_t)(m0 + srow) * K + cg;
    const bf16* gW = W + (size_t)(n0 + srow) * K + cg;
    bf16* lA0 = lA + t * 8;
    bf16* lB0 = lB + t * 8;

    for (int k0 = 0; k0 < K; k0 += BK) {
        __syncthreads();               // previous tiles fully consumed
#pragma unroll
        for (int c = 0; c < 4; c++)
            load_lds16(gA + (size_t)(32 * c) * K, lA0 + c * 2048);
#pragma unroll
        for (int c = 0; c < 2; c++)
            load_lds16(gW + (size_t)(32 * c) * K, lB0 + c * 2048);
        gA += BK; gW += BK;
        __syncthreads();               // drains vmcnt -> tiles published

#pragma unroll
        for (int ks = 0; ks < 2; ks++) {
            bf16x8 af[4], bfr[2];
            const int colp = ((((ks << 2) | quad) ^ (l15 & 7)) << 3);
#pragma unroll
            for (int mt = 0; mt < 4; mt++) {
                const int row = wm + mt * 16 + l15;
                af[mt] = *(const bf16x8*)(lA + row * BK + colp);
            }
#pragma unroll
            for (int nt = 0; nt < 2; nt++) {
                const int row = wn + nt * 16 + l15;
                bfr[nt] = *(const bf16x8*)(lB + row * BK + colp);
            }
#pragma unroll
            for (int mt = 0; mt < 4; mt++)
#pragma unroll
                for (int nt = 0; nt < 2; nt++)
                    acc[mt][nt] = __builtin_amdgcn_mfma_f32_16x16x32_bf16(
                        af[mt], bfr[nt], acc[mt][nt], 0, 0, 0);
        }
    }

    if constexpr (!TR) {
        // C/D layout: col = lane&15, row = quad*4 + i
#pragma unroll
        for (int nt = 0; nt < 2; nt++) {
            const int col = n0 + wn + nt * 16 + l15;
            const float bv = bias[col];
#pragma unroll
            for (int mt = 0; mt < 4; mt++) {
                const int rowb = m0 + wm + mt * 16 + quad * 4;
#pragma unroll
                for (int i = 0; i < 4; i++)
                    store_relu(&C[(size_t)(rowb + i) * N + col], acc[mt][nt][i] + bv);
            }
        }
    } else {
        // Transposed per-head epilogue into Vt_g[b][h][hd][s].
        __syncthreads();               // everyone done reading lA/lB
        bf16* trp = (bf16*)pool;       // tr[w][r][c] = trp[(w*32+r)*72 + c]
#pragma unroll
        for (int nt = 0; nt < 2; nt++) {
            const int col = n0 + wn + nt * 16 + l15;
            const float bv = bias[col];
#pragma unroll
            for (int mt = 0; mt < 4; mt++)
#pragma unroll
                for (int i = 0; i < 4; i++)
                    trp[((wave * 32) + nt * 16 + l15) * 72 + mt * 16 + quad * 4 + i] =
                        (bf16)fmaxf(acc[mt][nt][i] + bv, 0.0f);
        }
        __syncthreads();
        const int r2 = lane >> 3;          // 0..7
        const int c8 = (lane & 7) * 8;     // 0..56
#pragma unroll
        for (int rr = 0; rr < 4; rr++) {
            const int rt = rr * 8 + r2;                  // 0..31 (hd-dim col)
            const bf16x8 vv = *(const bf16x8*)&trp[((wave * 32) + rt) * 72 + c8];
            const int cg2 = n0 + wn + rt;                // global col
            const int h   = cg2 >> 6, hd = cg2 & 63;
            const int mg  = m0 + wm + c8;                // global row base
            const int b   = mg >> 11, s = mg & (Sc - 1);
            bf16* dst = (bf16*)C + ((size_t)(b * Hc + h) * 64 + hd) * Sc + s;
            *(bf16x8*)dst = vv;
        }
    }
}

template <typename TC, bool TR>
__global__ __launch_bounds__(256)
void gemm_bb(const bf16* __restrict__ A, const bf16* __restrict__ W,
             const float* __restrict__ bias, TC* __restrict__ C,
             int M, int N, int K) {
    __shared__ __align__(16) char pool[24576];
    gemm_body<TC, TR>(A, W, bias, C, pool, M, N, K);
}

// Batched QKV projection: blockIdx.z in {0,1,2} selects (A, W, bias, C);
// z<2 writes Qh/Kh (normal epilogue), z==2 writes VtG (TR epilogue).
__global__ __launch_bounds__(256)
void gemm_qkv3(const bf16* __restrict__ Aall, const bf16* __restrict__ Wall,
               const float* __restrict__ bq, const float* __restrict__ bk,
               const float* __restrict__ bv, bf16* __restrict__ Qh,
               bf16* __restrict__ vtg, int M, int N, int K) {
    __shared__ __align__(16) char pool[24576];
    const int z = blockIdx.z;
    const size_t E = (size_t)Bc * Sc * Dc;
    const bf16*  A    = Aall + (size_t)z * E;
    const bf16*  W    = Wall + (size_t)z * ((size_t)Dc * Dc);
    const float* bias = (z == 0) ? bq : (z == 1) ? bk : bv;
    if (z < 2)
        gemm_body<bf16, false>(A, W, bias, Qh + (size_t)z * E, pool, M, N, K);
    else
        gemm_body<bf16, true>(A, W, bias, vtg, pool, M, N, K);
}

// ---------------------------------------------------------------------------
// Flash attention — R8 inner structure, QI=1 (64 queries/block, 16/wave).
// Occupancy ladder: R10 QI=4 (2 blocks/CU, 11%) -> R11 QI=2 (4 blocks/CU,
// 19.5%, 111.6us, FETCH unchanged: L2 absorbed the 2x K/V re-reads) ->
// THIS ROUND QI=1 (resubmit; R12 was an infra failure): grid 64x32 = 2048
// blocks, LDS 24 KB (Pl[4][16][64]) -> 6 blocks/CU (LDS-capped) = 6
// waves/SIMD, VGPR ~70. Cost: staging + kf/vf fixed work amortizes over
// half the queries; L2/LDS pipes have measured headroom and the 1.5x wave
// pool interleaves the fixed work.
// Fixed-max softmax p=exp2(s) (post-ReLU scores bounded), ones-MFMA
// denominator, raw v_exp_f32, s_setprio, T14 issue-early K/V loads,
// stride-64 XOR-chunk swizzle, bh-on-x grid (XCD = linear%8 = bh%8).
// V pre-transposed per head: Vt_g[b][h][hd][s]. O accumulated transposed.
// ---------------------------------------------------------------------------
#define QI 1

__global__ __launch_bounds__(256)
void attn_flash(const bf16* __restrict__ Qh, const bf16* __restrict__ Kh,
                const bf16* __restrict__ Vt_g, bf16* __restrict__ Y) {
    __shared__ __align__(16) bf16 Kl[64][64];       // [key][hd]  swz   8192 B
    __shared__ __align__(16) bf16 Vl[64][64];       // [hd][key]  swz   8192 B
    __shared__ __align__(16) bf16 Pl[4][16][64];    // per-wave P^T swz  8192 B

    const int t    = threadIdx.x;
    const int lane = t & 63;
    const int wave = t >> 6;
    const int l15  = lane & 15;
    const int quad = lane >> 4;
    const int rswz = (l15 & 7) * 8;     // read-side swizzle key (row = ...+l15)

    const int bh = blockIdx.x;          // 0..63  (x so same-bh blocks share XCD)
    const int qt = blockIdx.y;          // 0..31
    const int b  = bh >> 4;
    const int h  = bh & 15;
    const int q0 = qt * 64;
    const size_t rowbase = (size_t)b * Sc;
    const size_t vhead   = (size_t)(b * Hc + h) * 64;

    const float qscale = 0.125f * 1.44269504f;
    bf16x8 qf[QI][2];
#pragma unroll
    for (int qi = 0; qi < QI; qi++) {
        const bf16* qp = Qh + (rowbase + q0 + wave * 16 + qi * 16 + l15) * (size_t)Dc + h * 64;
#pragma unroll
        for (int ks = 0; ks < 2; ks++) {
            const bf16x8 raw = *(const bf16x8*)(qp + ks * 32 + quad * 8);
#pragma unroll
            for (int j = 0; j < 8; j++) qf[qi][ks][j] = (bf16)((float)raw[j] * qscale);
        }
    }

    bf16x8 ones;
#pragma unroll
    for (int j = 0; j < 8; j++) ones[j] = (bf16)1.0f;

    f32x4 yacc[QI][4] = {};             // O^T: col=query=l15, row=hd
    f32x4 sacc[QI]    = {};             // denominator: all rows = sum_k p

    // staging map: thread covers row sr, logical cols [sc, sc+16)
    const int sr = t >> 2;
    const int sc = (t & 3) * 16;
    const int wswz = (sr & 7) * 8;      // write-side swizzle key
    const int sc0 = sc ^ wswz;          // swizzled chunk addresses (8-aligned)
    const int sc1 = (sc + 8) ^ wswz;
    constexpr int NT = Sc / 64;         // 32 key tiles

    const bf16* kp = Kh + (rowbase + sr) * (size_t)Dc + h * 64 + sc;
    const bf16* vp = Vt_g + (vhead + sr) * (size_t)Sc + sc;
    bf16x8 k0 = *(const bf16x8*)kp;
    bf16x8 k1 = *(const bf16x8*)(kp + 8);
    bf16x8 v0 = *(const bf16x8*)vp;
    bf16x8 v1 = *(const bf16x8*)(vp + 8);

    for (int kt = 0; kt < NT; kt++) {
        __syncthreads();                // prev tile fully consumed by all waves
        *(bf16x8*)&Kl[sr][sc0] = k0;
        *(bf16x8*)&Kl[sr][sc1] = k1;
        *(bf16x8*)&Vl[sr][sc0] = v0;
        *(bf16x8*)&Vl[sr][sc1] = v1;
        __syncthreads();                // tile published

        // T14 issue-early: fetch NEXT tile into regs; latency hides under
        // this tile's compute.
        if (kt + 1 < NT) {
            kp += (size_t)64 * Dc;
            vp += 64;
            k0 = *(const bf16x8*)kp;
            k1 = *(const bf16x8*)(kp + 8);
            v0 = *(const bf16x8*)vp;
            v1 = *(const bf16x8*)(vp + 8);
        }

        // ---- K fragments (A-operand [m=key][k=hd]) ----
        bf16x8 kf[4][2];
#pragma unroll
        for (int mt = 0; mt < 4; mt++) {
            kf[mt][0] = *(const bf16x8*)&Kl[mt * 16 + l15][(quad * 8) ^ rswz];
            kf[mt][1] = *(const bf16x8*)&Kl[mt * 16 + l15][(32 + quad * 8) ^ rswz];
        }

        // ---- phase A: QK^T -> exp2 -> P store ----
#pragma unroll
        for (int qi = 0; qi < QI; qi++) {
            f32x4 s[4];
            __builtin_amdgcn_s_setprio(1);
#pragma unroll
            for (int mt = 0; mt < 4; mt++) {
                s[mt] = (f32x4){0.f, 0.f, 0.f, 0.f};
                s[mt] = __builtin_amdgcn_mfma_f32_16x16x32_bf16(
                    kf[mt][0], qf[qi][0], s[mt], 0, 0, 0);
                s[mt] = __builtin_amdgcn_mfma_f32_16x16x32_bf16(
                    kf[mt][1], qf[qi][1], s[mt], 0, 0, 0);
            }
            __builtin_amdgcn_s_setprio(0);
#pragma unroll
            for (int mt = 0; mt < 4; mt++) {
                bf16x4 pk;
#pragma unroll
                for (int i = 0; i < 4; i++)
                    pk[i] = (bf16)__builtin_amdgcn_exp2f(s[mt][i]);
                *(bf16x4*)&Pl[wave][qi * 16 + l15][(mt * 16 + quad * 4) ^ rswz] = pk;
            }
        }

        // ---- V fragments (A-operand [m=hd][k=key]) ----
        bf16x8 vf[4][2];
#pragma unroll
        for (int nt = 0; nt < 4; nt++) {
            vf[nt][0] = *(const bf16x8*)&Vl[nt * 16 + l15][(quad * 8) ^ rswz];
            vf[nt][1] = *(const bf16x8*)&Vl[nt * 16 + l15][(32 + quad * 8) ^ rswz];
        }

        // ---- phase B: pf reads, then denominator + PV MFMAs ----
        bf16x8 pf[QI][2];
#pragma unroll
        for (int qi = 0; qi < QI; qi++) {
            pf[qi][0] = *(const bf16x8*)&Pl[wave][qi * 16 + l15][(quad * 8) ^ rswz];
            pf[qi][1] = *(const bf16x8*)&Pl[wave][qi * 16 + l15][(32 + quad * 8) ^ rswz];
        }
        __builtin_amdgcn_s_setprio(1);
#pragma unroll
        for (int qi = 0; qi < QI; qi++) {
            sacc[qi] = __builtin_amdgcn_mfma_f32_16x16x32_bf16(ones, pf[qi][0], sacc[qi], 0, 0, 0);
            sacc[qi] = __builtin_amdgcn_mfma_f32_16x16x32_bf16(ones, pf[qi][1], sacc[qi], 0, 0, 0);
#pragma unroll
            for (int nt = 0; nt < 4; nt++) {
                yacc[qi][nt] = __builtin_amdgcn_mfma_f32_16x16x32_bf16(
                    vf[nt][0], pf[qi][0], yacc[qi][nt], 0, 0, 0);
                yacc[qi][nt] = __builtin_amdgcn_mfma_f32_16x16x32_bf16(
                    vf[nt][1], pf[qi][1], yacc[qi][nt], 0, 0, 0);
            }
        }
        __builtin_amdgcn_s_setprio(0);
    }

    // ---- normalize (denominator replicated in every lane), store ----
#pragma unroll
    for (int qi = 0; qi < QI; qi++) {
        const float inv = 1.0f / sacc[qi][0];
        bf16* yp = Y + (rowbase + q0 + wave * 16 + qi * 16 + l15) * (size_t)Dc + h * 64;
#pragma unroll
        for (int nt = 0; nt < 4; nt++)
#pragma unroll
            for (int i = 0; i < 4; i++)
                yp[nt * 16 + quad * 4 + i] = (bf16)(yacc[qi][nt][i] * inv);
    }
}

// ---------------------------------------------------------------------------
extern "C" void kernel_launch(void* const* d_in, const int* in_sizes, int n_in,
                              void* d_out, int out_size, void* d_ws, size_t ws_size,
                              hipStream_t stream) {
    const float* q  = (const float*)d_in[0];
    const float* k  = (const float*)d_in[1];
    const float* v  = (const float*)d_in[2];
    const float* Wq = (const float*)d_in[3];
    const float* bq = (const float*)d_in[4];
    const float* Wk = (const float*)d_in[5];
    const float* bk = (const float*)d_in[6];
    const float* Wv = (const float*)d_in[7];
    const float* bv = (const float*)d_in[8];
    const float* Wo = (const float*)d_in[9];
    const float* bo = (const float*)d_in[10];
    float* out = (float*)d_out;

    const int M = Bc * Sc;   // 8192
    const int N = Dc;        // 1024
    const int K = Dc;        // 1024
    const size_t E  = (size_t)Bc * Sc * Dc;  // 8388608
    const size_t EW = (size_t)Dc * Dc;       // 1048576

    // d_out: Qh | Kh (bf16; dead before final GEMM writes fp32).
    bf16* Qh = (bf16*)d_out;

    const int n16  = (int)(E / 16);          // 524288
    const int n16w = (int)(EW / 16);         // 65536
    dim3 gw4(n16w / 256, 4);                 // 256 x 4 (all four weights)
    dim3 gg(M / BM, N / BN);                 // 64 x 16 = 1024 blocks (4/CU)
    dim3 ga(Bc * Hc, Sc / 64);               // 64 x 32 (bh on x: XCD locality)

    // Batched layout needs Aq|Ak|Av|VtG|W4 = (4E + 4EW) bf16 = 75.5 MB.
    const size_t need_batched = (4 * E + 4 * EW) * sizeof(bf16);

    if (ws_size >= need_batched) {
        // ---- 5-launch path (R10 best): cut inter-launch gaps ----
        bf16* Aq  = (bf16*)d_ws;             // also attn-output buffer later
        bf16* VtG = Aq + 3 * E;
        bf16* Wqb = VtG + E;
        bf16* Wob = Wqb + 3 * EW;
        bf16* tmpA = Aq;                     // attn Y (Aq dead after GEMMs)

        dim3 gc3(n16 / 256, 3);              // 2048 x 3
        dim3 gg3(M / BM, N / BN, 3);         // 64 x 16 x 3

        cvt_w4<<<gw4, 256, 0, stream>>>(Wq, Wk, Wv, Wo, Wqb);
        cvt_in3<<<gc3, 256, 0, stream>>>(q, k, v, Aq);
        gemm_qkv3<<<gg3, 256, 0, stream>>>(Aq, Wqb, bq, bk, bv, Qh, VtG, M, N, K);
        attn_flash<<<ga, 256, 0, stream>>>(Qh, Qh + E, VtG, tmpA);
        gemm_bb<float, false><<<gg, 256, 0, stream>>>(tmpA, Wob, bo, out, M, N, K);
    } else {
        // ---- R8 serial fallback (proven): tmpA | VtG | W4 = 41.9 MB ----
        bf16* tmpA = (bf16*)d_ws;
        bf16* VtG  = tmpA + E;
        bf16* Wqb  = VtG + E;
        bf16* Wkb  = Wqb + EW;
        bf16* Wvb  = Wkb + EW;
        bf16* Wob  = Wvb + EW;
        bf16* Kh   = Qh + E;

        dim3 gc(n16 / 256);                  // 2048

        cvt_w4<<<gw4, 256, 0, stream>>>(Wq, Wk, Wv, Wo, Wqb);

        cvt_f32_bf16<<<gc, 256, 0, stream>>>(q, tmpA, n16);
        gemm_bb<bf16, false><<<gg, 256, 0, stream>>>(tmpA, Wqb, bq, Qh, M, N, K);

        cvt_f32_bf16<<<gc, 256, 0, stream>>>(k, tmpA, n16);
        gemm_bb<bf16, false><<<gg, 256, 0, stream>>>(tmpA, Wkb, bk, Kh, M, N, K);

        cvt_f32_bf16<<<gc, 256, 0, stream>>>(v, tmpA, n16);
        gemm_bb<bf16, true><<<gg, 256, 0, stream>>>(tmpA, Wvb, bv, VtG, M, N, K);

        attn_flash<<<ga, 256, 0, stream>>>(Qh, Kh, VtG, tmpA);

        gemm_bb<float, false><<<gg, 256, 0, stream>>>(tmpA, Wob, bo, out, M, N, K);
    }
}